// Round 8
// baseline (274.061 us; speedup 1.0000x reference)
//
#include <hip/hip_runtime.h>
#include <math.h>
#include <stdint.h>

typedef unsigned short u16;
typedef unsigned int u32;
typedef __attribute__((ext_vector_type(8))) short bf16x8;   // 8 bf16 (4 VGPRs)
typedef __attribute__((ext_vector_type(4))) float f32x4;    // MFMA C/D

#define T_TOK 16384
#define NEXP 8

__device__ __forceinline__ u16 f2bf(float f) {
    union { float f; unsigned u; } v; v.f = f;
    unsigned u = v.u;
    return (u16)((u + 0x7fffu + ((u >> 16) & 1u)) >> 16);   // RNE
}

// exact-GELU via Abramowitz-Stegun 7.1.26 erf (max abs err 1.5e-7 << bf16 ulp)
__device__ __forceinline__ float gelu_exact(float h) {
    float x  = h * 0.70710678118654752f;
    float ax = fabsf(x);
    float t  = __builtin_amdgcn_rcpf(1.f + 0.3275911f * ax);
    float p  = t * (0.254829592f + t * (-0.284496736f + t * (1.421413741f +
               t * (-1.453152027f + t * 1.061405429f))));
    float er = 1.f - p * __expf(-x * x);
    er = (x < 0.f) ? -er : er;
    return 0.5f * h * (1.f + er);
}

// async global->LDS, 16B per lane. LDS dest must be wave-uniform base + lane*16.
__device__ __forceinline__ void gload16(const void* g, void* l) {
    __builtin_amdgcn_global_load_lds(
        (const __attribute__((address_space(1))) u32*)(unsigned long long)(uintptr_t)g,
        (__attribute__((address_space(3))) u32*)(unsigned int)(uintptr_t)l,
        16, 0, 0);
}

__device__ __forceinline__ double shfl_xor_dbl(double v, int m) {
    union { double d; int i[2]; } u; u.d = v;
    u.i[0] = __shfl_xor(u.i[0], m, 64);
    u.i[1] = __shfl_xor(u.i[1], m, 64);
    return u.d;
}

// ---- weights -> MFMA fragment layout, bf16 ----
// input viewed as [e][K][N] f32. output frag f = nf*(K/32)+kf: u16 at ((f*64+lane)*8+j)
// = element (col = nf*16 + (lane&15), k = kf*32 + (lane>>4)*8 + j)
__global__ __launch_bounds__(256) void wfrag_kernel(
    const float* __restrict__ W1, const float* __restrict__ W2,
    u16* __restrict__ W1f, u16* __restrict__ W2f) {
    __shared__ float tile[32][65];
    int id = blockIdx.x;
    const float* src; u16* dst; int K, N, e, k0, n0;
    if (id < 1536) {            // 8e x 16kf x 12ngrp
        K = 512; N = 768; e = id / 192; int rem = id % 192;
        k0 = (rem / 12) * 32; n0 = (rem % 12) * 64;
        src = W1; dst = W1f;
    } else {                    // 8e x 24kf x 8ngrp
        id -= 1536;
        K = 768; N = 512; e = id / 192; int rem = id % 192;
        k0 = (rem / 8) * 32; n0 = (rem % 8) * 64;
        src = W2; dst = W2f;
    }
    int tid = threadIdx.x;
    const float* s = src + (size_t)e * K * N + (size_t)k0 * N + n0;
#pragma unroll
    for (int it = 0; it < 8; it++) {
        int idx = it * 256 + tid;
        int kk = idx >> 6, nn = idx & 63;
        tile[kk][nn] = s[(size_t)kk * N + nn];
    }
    __syncthreads();
    int w = tid >> 6, lane = tid & 63;
    int c = w * 16 + (lane & 15), ksub = (lane >> 4) * 8;
    union { u16 a[8]; uint4 v; } o;
#pragma unroll
    for (int j = 0; j < 8; j++) o.a[j] = f2bf(tile[ksub + j][c]);
    int KF = K >> 5;
    int nf = (n0 >> 4) + w, kf = k0 >> 5;
    *(uint4*)(dst + (size_t)e * 393216 + ((size_t)(nf * KF + kf) * 64 + lane) * 8) = o.v;
}

// ------ R1: routing math (fp64), emits xb (bf16 x), packed choices, per-block counts ------
__global__ __launch_bounds__(256) void router_kernel(
    const float* __restrict__ x, const float* __restrict__ Wg,
    const float* __restrict__ bg,
    u16* __restrict__ xb, float4* __restrict__ packed, int* __restrict__ blockcnt) {
    __shared__ double wgd[4096];
    __shared__ int lcnt[8];
    int tid = threadIdx.x;
    if (tid < 8) lcnt[tid] = 0;
    for (int i = tid; i < 4096; i += 256) {
        int k = i >> 3, j = i & 7;
        int slot = (j + ((k >> 2) & 7)) & 7;
        wgd[k * 8 + slot] = (double)Wg[i];
    }
    __syncthreads();

    int w = tid >> 6, lane = tid & 63;
    int tg = lane >> 3, sl = lane & 7;
    int t  = blockIdx.x * 32 + w * 8 + tg;
    const float* xr = x  + (size_t)t * 512;
    u16*       xrow = xb + (size_t)t * 512;

    float4 xv[16];
#pragma unroll
    for (int it = 0; it < 16; it++)
        xv[it] = *(const float4*)(xr + it * 32 + sl * 4);

#pragma unroll
    for (int it = 0; it < 16; it++) {
        ushort4 o;
        o.x = f2bf(xv[it].x); o.y = f2bf(xv[it].y);
        o.z = f2bf(xv[it].z); o.w = f2bf(xv[it].w);
        *(ushort4*)(xrow + it * 32 + sl * 4) = o;
    }

    int jr[8];
#pragma unroll
    for (int j = 0; j < 8; j++) jr[j] = (j + sl) & 7;

    double acc[8];
#pragma unroll
    for (int j = 0; j < 8; j++) acc[j] = 0.0;
#pragma unroll
    for (int it = 0; it < 16; it++) {
        float vv[4] = { xv[it].x, xv[it].y, xv[it].z, xv[it].w };
#pragma unroll
        for (int q = 0; q < 4; q++) {
            int k = it * 32 + sl * 4 + q;
            double dv = (double)vv[q];
            const double* wr = wgd + (size_t)k * 8;
#pragma unroll
            for (int j = 0; j < 8; j++)
                acc[j] += dv * wr[jr[j]];
        }
    }
#pragma unroll
    for (int j = 0; j < 8; j++) {
        acc[j] += shfl_xor_dbl(acc[j], 1);
        acc[j] += shfl_xor_dbl(acc[j], 2);
        acc[j] += shfl_xor_dbl(acc[j], 4);
    }

    double s[8];
#pragma unroll
    for (int j = 0; j < 8; j++) s[j] = acc[j] + (double)bg[j];
    int i0 = 0;
#pragma unroll
    for (int j = 1; j < 8; j++) if (s[j] > s[i0]) i0 = j;
    int i1 = (i0 == 0) ? 1 : 0;
#pragma unroll
    for (int j = 0; j < 8; j++) if (j != i0 && s[j] > s[i1]) i1 = j;
    float d  = expf((float)(s[i1] - s[i0]));
    float g0 = 1.f / (1.f + d);
    float g1 = d / (1.f + d);

    if (sl == 0) {
        packed[t] = make_float4(__int_as_float(i0), __int_as_float(i1), g0, g1);
        atomicAdd(&lcnt[i0], 1);   // LDS atomics only
        atomicAdd(&lcnt[i1], 1);
    }
    __syncthreads();
    if (tid < 8) blockcnt[blockIdx.x * 8 + tid] = lcnt[tid];
}

// ------ R2: exclusive scan blockcnt[512][8] -> blockoff + counts ------
__global__ __launch_bounds__(512) void scan_kernel(const int* __restrict__ blockcnt,
                                                   int* __restrict__ blockoff,
                                                   int* __restrict__ counts) {
    int w = threadIdx.x >> 6;    // expert
    int lane = threadIdx.x & 63;
    int v[8]; int partial = 0;
#pragma unroll
    for (int i = 0; i < 8; i++) { v[i] = blockcnt[(lane * 8 + i) * 8 + w]; partial += v[i]; }
    int inc = partial;
#pragma unroll
    for (int d = 1; d < 64; d <<= 1) {
        int tt = __shfl_up(inc, d, 64);
        if (lane >= d) inc += tt;
    }
    int run = inc - partial;
#pragma unroll
    for (int i = 0; i < 8; i++) { blockoff[(lane * 8 + i) * 8 + w] = run; run += v[i]; }
    if (lane == 63) counts[w] = inc;
}

// ------ R3: scatter tokens into per-expert lists via ballot ranks ------
__global__ void scatter_kernel(const float4* __restrict__ packed,
                               const int* __restrict__ blockoff,
                               int* __restrict__ tokenlist, float* __restrict__ gatelist) {
    int b = blockIdx.x, i = threadIdx.x;
    int t = b * 32 + (i >> 1), p = i & 1;
    float4 pk = packed[t];
    int   e = p ? __float_as_int(pk.y) : __float_as_int(pk.x);
    float g = p ? pk.w : pk.z;
    unsigned long long lt = (1ull << i) - 1ull;
    int slot = 0;
#pragma unroll
    for (int j = 0; j < 8; j++) {
        unsigned long long m = __ballot(e == j);
        if (e == j) slot = blockoff[b * 8 + j] + __popcll(m & lt);
    }
    tokenlist[e * T_TOK + slot] = t;
    gatelist [e * T_TOK + slot] = g;
}

// ---------------- fused expert MLP: 64 tokens/block, 8 waves, weights streamed as frags ----------------
// expert = blockIdx&7 -> XCD-affine L2 residency of that expert's 1.5MB weights.
// NEW (r8): double-buffered register prefetch of B-fragments one K-step ahead
// (round-7 profile: 15% MfmaUtil with ~2000cy/iter vs ~470cy MFMA — serialized L2 loads).
__global__ __launch_bounds__(512, 2) void fused_expert_kernel(
    const u16* __restrict__ xb, const u16* __restrict__ W1f, const u16* __restrict__ W2f,
    const float* __restrict__ b1, const float* __restrict__ b2,
    const int* __restrict__ counts, const int* __restrict__ tokenlist,
    const float* __restrict__ gatelist, float* __restrict__ out)
{
    int e = blockIdx.x & 7;
    int g = blockIdx.x >> 3;
    int cnt = counts[e];
    int row0 = g * 64;
    if (row0 >= cnt) return;

    __shared__ __align__(16) char smem[131840];
    char* Xl = smem;                  // [64][256] bf16 (K-half), swizzled, 32 KB
    char* Hl = smem + 32768;          // [64][768] bf16, swizzled, 96 KB
    int*   tokrow  = (int*)(smem + 131072);
    float* gaterow = (float*)(smem + 131328);

    int tid = threadIdx.x;
    if (tid < 64) {
        int slot = row0 + tid;
        int cl = slot < cnt ? slot : cnt - 1;
        tokrow[tid]  = tokenlist[e * T_TOK + cl];
        gaterow[tid] = gatelist[e * T_TOK + cl];
    }
    __syncthreads();

    int lane = tid & 63, w = tid >> 6;
    int lr = lane & 15, hk = lane >> 4;

    // staging srcs: dest chunk linear, source chunk pre-swizzled (involution with reads)
    const u16* aptr[4];
#pragma unroll
    for (int i = 0; i < 4; i++) {
        int chunk = i * 512 + tid;
        int row = chunk >> 5, c = chunk & 31;
        int csrc = (c & 24) | ((c & 7) ^ (row & 7));
        aptr[i] = xb + (size_t)tokrow[row] * 512 + csrc * 8;
    }

    const u16* w1b = W1f + (size_t)e * 393216;
    const u16* w2b = W2f + (size_t)e * 393216;

    auto ldb1 = [&](int kf, int ni) -> bf16x8 {
        int nf = w * 6 + ni;
        return *(const bf16x8*)(w1b + ((nf * 16 + kf) * 64 + lane) * 8);
    };
    auto lda1 = [&](int kf, int mi) -> bf16x8 {
        int row = mi * 16 + lr;
        int chunk = (kf & 7) * 4 + hk;
        int sw = (chunk & 24) | ((chunk & 7) ^ (row & 7));
        return *(const bf16x8*)(Xl + row * 512 + sw * 16);
    };

    f32x4 acc1[4][6];
#pragma unroll
    for (int mi = 0; mi < 4; mi++)
#pragma unroll
        for (int ni = 0; ni < 6; ni++)
            acc1[mi][ni] = (f32x4){0.f, 0.f, 0.f, 0.f};

    bf16x8 bA[6], bB[6];
#pragma unroll
    for (int h = 0; h < 2; h++) {
        if (h) __syncthreads();                   // all waves done reading half 0
#pragma unroll
        for (int i = 0; i < 4; i++)
            gload16(aptr[i] + h * 256, Xl + (i * 512 + tid) * 16);
        // prefetch this half's first B-frags while staging is in flight
#pragma unroll
        for (int ni = 0; ni < 6; ni++) bA[ni] = ldb1(h * 8, ni);
        __syncthreads();                          // staging complete
#pragma unroll
        for (int ks = 0; ks < 8; ks += 2) {
            int kf = h * 8 + ks;
            // prefetch kf+1 B-frags (grouped, independent -> pipelined in L2)
#pragma unroll
            for (int ni = 0; ni < 6; ni++) bB[ni] = ldb1(kf + 1, ni);
            bf16x8 a[4];
#pragma unroll
            for (int mi = 0; mi < 4; mi++) a[mi] = lda1(kf, mi);
#pragma unroll
            for (int mi = 0; mi < 4; mi++)
#pragma unroll
                for (int ni = 0; ni < 6; ni++)
                    acc1[mi][ni] = __builtin_amdgcn_mfma_f32_16x16x32_bf16(
                        a[mi], bA[ni], acc1[mi][ni], 0, 0, 0);
            if (ks < 6) {
#pragma unroll
                for (int ni = 0; ni < 6; ni++) bA[ni] = ldb1(kf + 2, ni);
            }
#pragma unroll
            for (int mi = 0; mi < 4; mi++) a[mi] = lda1(kf + 1, mi);
#pragma unroll
            for (int mi = 0; mi < 4; mi++)
#pragma unroll
                for (int ni = 0; ni < 6; ni++)
                    acc1[mi][ni] = __builtin_amdgcn_mfma_f32_16x16x32_bf16(
                        a[mi], bB[ni], acc1[mi][ni], 0, 0, 0);
        }
    }

    // bias + GELU -> H LDS (swizzled)
    float b1v[6];
#pragma unroll
    for (int ni = 0; ni < 6; ni++) b1v[ni] = b1[e * 768 + w * 96 + ni * 16 + lr];
#pragma unroll
    for (int ni = 0; ni < 6; ni++) {
        int col = w * 96 + ni * 16 + lr;
        int cb = col >> 3;                 // 16B chunk index within row
        int lo = (col * 2) & 15;
#pragma unroll
        for (int mi = 0; mi < 4; mi++) {
#pragma unroll
            for (int r = 0; r < 4; r++) {
                int row = mi * 16 + hk * 4 + r;
                int sw = (cb & ~7) | ((cb & 7) ^ (row & 7));
                *(u16*)(Hl + row * 1536 + sw * 16 + lo) =
                    f2bf(gelu_exact(acc1[mi][ni][r] + b1v[ni]));
            }
        }
    }

    auto ldb2 = [&](int ks, int ni) -> bf16x8 {
        int nf = w * 4 + ni;
        return *(const bf16x8*)(w2b + ((nf * 24 + ks) * 64 + lane) * 8);
    };
    auto lda2 = [&](int ks, int mi) -> bf16x8 {
        int row = mi * 16 + lr;
        int chunk = ks * 4 + hk;
        int sw = (chunk & ~7) | ((chunk & 7) ^ (row & 7));
        return *(const bf16x8*)(Hl + row * 1536 + sw * 16);
    };

    // prefetch GEMM2's first B-frags BEFORE the barrier (global, no LDS dependency)
    bf16x8 cA[4], cB[4];
#pragma unroll
    for (int ni = 0; ni < 4; ni++) cA[ni] = ldb2(0, ni);
    __syncthreads();

    f32x4 acc2[4][4];
#pragma unroll
    for (int mi = 0; mi < 4; mi++)
#pragma unroll
        for (int ni = 0; ni < 4; ni++)
            acc2[mi][ni] = (f32x4){0.f, 0.f, 0.f, 0.f};

#pragma unroll
    for (int ks = 0; ks < 24; ks += 2) {
#pragma unroll
        for (int ni = 0; ni < 4; ni++) cB[ni] = ldb2(ks + 1, ni);
        bf16x8 a[4];
#pragma unroll
        for (int mi = 0; mi < 4; mi++) a[mi] = lda2(ks, mi);
#pragma unroll
        for (int mi = 0; mi < 4; mi++)
#pragma unroll
            for (int ni = 0; ni < 4; ni++)
                acc2[mi][ni] = __builtin_amdgcn_mfma_f32_16x16x32_bf16(
                    a[mi], cA[ni], acc2[mi][ni], 0, 0, 0);
        if (ks < 22) {
#pragma unroll
            for (int ni = 0; ni < 4; ni++) cA[ni] = ldb2(ks + 2, ni);
        }
#pragma unroll
        for (int mi = 0; mi < 4; mi++) a[mi] = lda2(ks + 1, mi);
#pragma unroll
        for (int mi = 0; mi < 4; mi++)
#pragma unroll
            for (int ni = 0; ni < 4; ni++)
                acc2[mi][ni] = __builtin_amdgcn_mfma_f32_16x16x32_bf16(
                    a[mi], cB[ni], acc2[mi][ni], 0, 0, 0);
    }

    // epilogue: out[token] += gate * (O + b2)
    float b2v[4];
#pragma unroll
    for (int ni = 0; ni < 4; ni++) b2v[ni] = b2[e * 512 + w * 64 + ni * 16 + lr];
#pragma unroll
    for (int mi = 0; mi < 4; mi++) {
#pragma unroll
        for (int r = 0; r < 4; r++) {
            int row  = mi * 16 + hk * 4 + r;
            int slot = row0 + row;
            if (slot < cnt) {
                int   tok = tokrow[row];
                float gg  = gaterow[row];
                float* orow = out + (size_t)tok * 512 + w * 64 + lr;
#pragma unroll
                for (int ni = 0; ni < 4; ni++)
                    atomicAdd(orow + ni * 16, (acc2[mi][ni][r] + b2v[ni]) * gg);
            }
        }
    }
}

extern "C" void kernel_launch(void* const* d_in, const int* in_sizes, int n_in,
                              void* d_out, int out_size, void* d_ws, size_t ws_size,
                              hipStream_t stream) {
    const float* x  = (const float*)d_in[0];   // [8,2048,512]
    const float* Wg = (const float*)d_in[1];   // [512,8]
    const float* bg = (const float*)d_in[2];   // [8]
    const float* W1 = (const float*)d_in[3];   // [8,512,768]
    const float* b1 = (const float*)d_in[4];   // [8,768]
    const float* W2 = (const float*)d_in[5];   // [8,768,512]
    const float* b2 = (const float*)d_in[6];   // [8,512]
    float* out = (float*)d_out;                // [8,2048,512] fp32

    char* ws = (char*)d_ws;
    int*    counts    = (int*)(ws + 0);                   // 8 int
    int*    blockcnt  = (int*)(ws + 1024);                // 512*8 int
    int*    blockoff  = (int*)(ws + 17408);               // 512*8 int
    float4* packed    = (float4*)(ws + 33792);            // 16384*16 B
    int*    tokenlist = (int*)(ws + 295936);              // 8*16384 int
    float*  gatelist  = (float*)(ws + 820224);            // 8*16384 f32
    u16*    xb        = (u16*)(ws + 1344512);             // 16 MB
    u16*    W1f       = (u16*)(ws + 18121728);            // 6 MB frag-layout
    u16*    W2f       = (u16*)(ws + 24413184);            // 6 MB frag-layout
    (void)in_sizes; (void)n_in; (void)ws_size;

    hipMemsetAsync(d_out, 0, (size_t)out_size * sizeof(float), stream);

    router_kernel<<<512, 256, 0, stream>>>(x, Wg, bg, xb, packed, blockcnt);
    wfrag_kernel<<<3072, 256, 0, stream>>>(W1, W2, W1f, W2f);
    scan_kernel<<<1, 512, 0, stream>>>(blockcnt, blockoff, counts);
    scatter_kernel<<<512, 64, 0, stream>>>(packed, blockoff, tokenlist, gatelist);

    fused_expert_kernel<<<2048, 512, 0, stream>>>(xb, W1f, W2f, b1, b2,
                                                  counts, tokenlist, gatelist, out);
}